// Round 17
// baseline (159.043 us; speedup 1.0000x reference)
//
#include <hip/hip_runtime.h>

// ---- problem constants ----
#define N_ROWS 16384   // 8*16*128
#define DIM    256
#define K_CODES 8192

// i8 quantization scale: max|N(0,1)| over 6.3M samples ~= 5.2 < 5.5
#define QSCALE (127.0f / 5.5f)

// output layout (flat float32, return order)
#define OFF_ZQ   0
#define OFF_LOSS 4194304
#define OFF_IDX  4194305
#define OFF_CB   4210689
#define OFF_CNT  6307841
#define OFF_MEAN 6316033

// d_out scratch (all consumed before the real outputs overwrite, stream-ordered):
//   zqp   [0 .. 1048576) floats       — permuted i8 z (4MB), dead after dist
//   cqp   [1048576 .. 1572864) floats — permuted i8 codebook (2MB), dead after dist
//   cand  [4210692 .. 5259268) floats — u32[16384][64] keys, dead after rescore
//         (inside CB region, overwritten by merge afterwards — stream-ordered)
#define POFF_ZQP   0
#define POFF_CQP   1048576
#define POFF_CAND  4210692

// workspace layout (bytes) — fits R1-proven 8.65MB footprint
#define WS_CNT    0        // u32[8192]   -> 32768
#define WS_CN8    32768    // u32[8192]   -> 65536  (biased<<7 codebook norms)
#define WS_LOSSP  65536    // f32[4096]   -> 81920
#define WS_N      81920    // f32         -> 81924
#define WS_MEAN   98304    // f32[8192*256] -> 8486912

typedef int i32x4 __attribute__((ext_vector_type(4)));
typedef float f32x4 __attribute__((ext_vector_type(4)));

__device__ inline signed char q8(float v) {
    float x = v * QSCALE;
    x = fminf(fmaxf(x, -127.0f), 127.0f);
    return (signed char)__float2int_rn(x);
}

// ---------------- prep: quantize z + cb to permuted i8 planes + biased cnorm + zero meanAcc/counts ----------------
// zqp bytes: [zblk(128)][kc(4)][gk(4)][r(128)][16 i8]
// cqp bytes: [cblk(32)][kc(4)][gk(4)][r(256)][16 i8]
__global__ __launch_bounds__(256) void prep_kernel(const float* __restrict__ z,
                                                   const float* __restrict__ cb,
                                                   signed char* __restrict__ zqp,
                                                   signed char* __restrict__ cqp,
                                                   unsigned* __restrict__ cn8,
                                                   float* __restrict__ meanAcc,
                                                   unsigned* __restrict__ counts) {
    int b = blockIdx.x;
    if (b < 1024) {                       // ---- z quantize: one 16-elem granule per thread
        int g = b * 256 + threadIdx.x;
        int row = g >> 4, gr = g & 15;
        const float* src = z + (size_t)row * DIM + gr * 16;
        char cq[16];
        #pragma unroll
        for (int t = 0; t < 4; ++t) {
            float4 v = *(const float4*)(src + t * 4);
            cq[t * 4 + 0] = q8(v.x); cq[t * 4 + 1] = q8(v.y);
            cq[t * 4 + 2] = q8(v.z); cq[t * 4 + 3] = q8(v.w);
        }
        int zblk = row >> 7, r = row & 127, kc = gr >> 2, gk = gr & 3;
        size_t o = ((size_t)((zblk * 4 + kc) * 4 + gk) * 128 + r) * 16;
        *(i32x4*)(zqp + o) = *(const i32x4*)cq;
    } else if (b < 3072) {                // ---- cb quantize + biased int cnorm: one wave per row
        int w = threadIdx.x >> 6, lane = threadIdx.x & 63;
        int row = (b - 1024) * 4 + w;
        float4 v = *(const float4*)(cb + (size_t)row * DIM + lane * 4);
        char cq[4] = {q8(v.x), q8(v.y), q8(v.z), q8(v.w)};
        int gr = lane >> 2;               // granule 0..15
        int kc = gr >> 2, gk = gr & 3;
        int cblk = row >> 8, r = row & 255;
        size_t o = ((size_t)((cblk * 4 + kc) * 4 + gk) * 256 + r) * 16 + (lane & 3) * 4;
        *(int*)(cqp + o) = *(const int*)cq;
        int s = (int)cq[0] * cq[0] + (int)cq[1] * cq[1] + (int)cq[2] * cq[2] + (int)cq[3] * cq[3];
        #pragma unroll
        for (int off = 32; off; off >>= 1) s += __shfl_down(s, off, 64);
        if (lane == 0) cn8[row] = ((unsigned)(s + 16777216)) << 7;   // (cnorm + 2^24) << 7
    } else if (b < 4096) {                // ---- zero meanAcc: 8 floats per thread
        int g = (b - 3072) * 256 + threadIdx.x;
        float4 zero = {0.f, 0.f, 0.f, 0.f};
        float4* p = (float4*)(meanAcc + (size_t)g * 8);
        p[0] = zero; p[1] = zero;
    } else {                              // ---- zero counts (b == 4096)
        #pragma unroll
        for (int i = 0; i < 32; ++i) counts[threadIdx.x * 32 + i] = 0u;
    }
}

// ---------------- distance screen: i8 MFMA, pinned 1-deep prefetch, 3-op keys ----------------
// block = 256 codes x 64 z, 4 waves; wave = 64 codes x 64 z (4i x 4j of 16x16x64_i8, 4 kc).
// R9-proven read swizzle; R11-proven sched_barrier prefetch pin.
// launch_bounds (256,3): VGPR 72 — (256,4) caps VGPR at 64 and DE-PIPELINES the
// prefetch (R15: dist 59.7->91.2us). Do not raise occupancy at the cost of the pipeline.
// key = ((cn8 - (acc<<8)) & 0xFFFFFF00) | id  ==  (((cn-2acc)+2^24)>>1)<<8 | id  (exact)
__global__ __launch_bounds__(256, 3) void dist_kernel(const signed char* __restrict__ zqp,
                                                      const signed char* __restrict__ cqp,
                                                      const unsigned* __restrict__ cn8,
                                                      unsigned* __restrict__ cand) {
    __shared__ unsigned red[4][64][2];

    const int tid = threadIdx.x;
    const int w = tid >> 6, lane = tid & 63;
    const int c16 = lane & 15, g4 = lane >> 4;

    int b = blockIdx.x;
    int xcd = b & 7;
    int wgx = b >> 3;
    int cbY = wgx >> 5;              // slow: code block (256 codes)
    int zbX = xcd * 32 + (wgx & 31); // fast: z block (64 rows), XCD-contiguous

    i32x4 acc[4][4];
    #pragma unroll
    for (int i = 0; i < 4; ++i)
        #pragma unroll
        for (int j = 0; j < 4; ++j) acc[i][j] = 0;

    const signed char* Abase = cqp + (size_t)cbY * 65536 + g4 * 4096 + (w * 64 + c16) * 16;
    const signed char* Bbase = zqp + (size_t)(zbX >> 1) * 32768 + g4 * 2048 + ((zbX & 1) * 64 + c16) * 16;

    i32x4 a[4], b_[4], an[4], bn[4];
    #pragma unroll
    for (int i = 0; i < 4; ++i) a[i] = *(const i32x4*)(Abase + i * 256);
    #pragma unroll
    for (int j = 0; j < 4; ++j) b_[j] = *(const i32x4*)(Bbase + j * 256);

    #pragma unroll
    for (int kc = 0; kc < 4; ++kc) {
        if (kc < 3) {
            #pragma unroll
            for (int i = 0; i < 4; ++i) an[i] = *(const i32x4*)(Abase + (kc + 1) * 16384 + i * 256);
            #pragma unroll
            for (int j = 0; j < 4; ++j) bn[j] = *(const i32x4*)(Bbase + (kc + 1) * 8192 + j * 256);
            __builtin_amdgcn_sched_barrier(0);   // prefetch must not sink past the MFMAs
        }
        #pragma unroll
        for (int i = 0; i < 4; ++i)
            #pragma unroll
            for (int j = 0; j < 4; ++j)
                acc[i][j] = __builtin_amdgcn_mfma_i32_16x16x64_i8(a[i], b_[j], acc[i][j], 0, 0, 0);
        if (kc < 3) {
            __builtin_amdgcn_sched_barrier(0);   // register rotation stays behind MFMAs
            #pragma unroll
            for (int i = 0; i < 4; ++i) a[i] = an[i];
            #pragma unroll
            for (int j = 0; j < 4; ++j) b_[j] = bn[j];
        }
    }

    unsigned cn[4][4];
    #pragma unroll
    for (int i = 0; i < 4; ++i)
        #pragma unroll
        for (int reg = 0; reg < 4; ++reg)
            cn[i][reg] = cn8[cbY * 256 + w * 64 + i * 16 + g4 * 4 + reg];

    // epilogue: top-2 per (z-col, 256-code block); C/D: col=lane&15 (z), row=(lane>>4)*4+reg
    #pragma unroll
    for (int j = 0; j < 4; ++j) {
        unsigned b1 = 0xFFFFFFFFu, b2 = 0xFFFFFFFFu;
        #pragma unroll
        for (int i = 0; i < 4; ++i) {
            #pragma unroll
            for (int reg = 0; reg < 4; ++reg) {
                unsigned id = (unsigned)(w * 64 + i * 16 + g4 * 4 + reg);
                unsigned key = ((cn[i][reg] - ((unsigned)acc[i][j][reg] << 8)) & 0xFFFFFF00u) | id;
                unsigned mx = max(b1, key);
                b1 = min(b1, key);
                b2 = min(b2, mx);
            }
        }
        #pragma unroll
        for (int off = 16; off <= 32; off <<= 1) {
            unsigned o1 = __shfl_xor(b1, off), o2 = __shfl_xor(b2, off);
            unsigned m1 = min(b1, o1);
            unsigned hi = max(b1, o1);
            b1 = m1;
            b2 = min(min(b2, o2), hi);
        }
        if (lane < 16) { red[w][j * 16 + lane][0] = b1; red[w][j * 16 + lane][1] = b2; }
    }
    __syncthreads();
    if (tid < 64) {
        unsigned b1 = 0xFFFFFFFFu, b2 = 0xFFFFFFFFu;
        #pragma unroll
        for (int t = 0; t < 4; ++t) {
            unsigned o1 = red[t][tid][0], o2 = red[t][tid][1];
            unsigned m1 = min(b1, o1);
            unsigned hi = max(b1, o1);
            b1 = m1;
            b2 = min(min(b2, o2), hi);
        }
        size_t base = (size_t)(zbX * 64 + tid) * 64 + cbY * 2;   // row-major
        *(uint2*)(cand + base) = make_uint2(b1, b2);
    }
}

// ---------------- rescore (fp64 within margin) + assign, fused ----------------
// Direct meanAcc atomics are back: R11's 86us was the uncoalesced cbY-major cand
// gather (fixed in R12 with row-major), NOT the atomics. 4.19M lane-RMWs to
// mostly-distinct addresses (~2 rows/code) ~ few us. Kills prefix/scatter/bucket_sum.
__global__ __launch_bounds__(256) void rescore_assign_kernel(const float* __restrict__ z,
                                                             const float* __restrict__ cb,
                                                             const unsigned* __restrict__ cand,
                                                             float* __restrict__ zq_out,
                                                             float* __restrict__ idx_out,
                                                             unsigned* __restrict__ counts,
                                                             float* __restrict__ meanAcc,
                                                             float* __restrict__ lossPart) {
    __shared__ float lred[4];
    int w = threadIdx.x >> 6, lane = threadIdx.x & 63;
    int row = blockIdx.x * 4 + w;
    unsigned k32 = cand[(size_t)row * 64 + lane];   // coalesced row-major gather
    unsigned m = k32;
    #pragma unroll
    for (int off = 32; off; off >>= 1) {
        unsigned o = __shfl_xor(m, off);
        if (o < m) m = o;
    }
    // margin: 5.25 real / (5.5/127)^2 = 2800 d-units = 1400 half-units (key>>8 domain)
    unsigned vmin = m >> 8;
    unsigned vme = k32 >> 8;
    int mycode = (lane >> 1) * 256 + (int)(k32 & 0xFFu);
    unsigned long long mask = __ballot(vme <= vmin + 1400u);

    float4 zv = *(const float4*)(z + (size_t)row * DIM + lane * 4);
    double bd = 1e300;
    int bc = 0x7fffffff;
    while (mask) {
        int src = __ffsll((unsigned long long)mask) - 1;
        mask &= mask - 1;
        int code = __shfl(mycode, src);
        float4 c4 = *(const float4*)(cb + (size_t)code * DIM + lane * 4);
        double d0 = (double)zv.x - c4.x, d1 = (double)zv.y - c4.y;
        double d2 = (double)zv.z - c4.z, d3 = (double)zv.w - c4.w;
        double s = d0 * d0 + d1 * d1 + d2 * d2 + d3 * d3;
        #pragma unroll
        for (int off = 32; off; off >>= 1) s += __shfl_xor(s, off);
        if (s < bd || (s == bd && code < bc)) { bd = s; bc = code; }
    }

    float4 cv = *(const float4*)(cb + (size_t)bc * DIM + lane * 4);
    *(float4*)(zq_out + (size_t)row * DIM + lane * 4) = cv;
    float* mp = meanAcc + (size_t)bc * DIM + lane * 4;
    atomicAdd(mp + 0, zv.x);
    atomicAdd(mp + 1, zv.y);
    atomicAdd(mp + 2, zv.z);
    atomicAdd(mp + 3, zv.w);
    if (lane == 0) {
        idx_out[row] = (float)bc;
        atomicAdd(counts + bc, 1u);
        lred[w] = (float)bd;                // loss term = exact fp64 distance of winner
    }
    __syncthreads();
    if (threadIdx.x == 0)
        lossPart[blockIdx.x] = lred[0] + lred[1] + lred[2] + lred[3];
}

// ---------------- count finalize: newCount + n + loss (single block) ----------------
__global__ __launch_bounds__(1024) void count_final_kernel(const unsigned* __restrict__ counts,
                                                           const float* __restrict__ ema_count,
                                                           const float* __restrict__ lossPart,
                                                           float* __restrict__ newCount_out,
                                                           float* __restrict__ nOut,
                                                           float* __restrict__ loss_out) {
    __shared__ float fred[1024];
    const float OMD = 0.01f;
    int tid = threadIdx.x;
    int base = tid * 8;

    float es = 0.f;
    #pragma unroll
    for (int i = 0; i < 8; ++i) {
        float e = ema_count[base + i];
        es += e;
        newCount_out[base + i] = 0.99f * e + OMD * (float)counts[base + i];
    }
    fred[tid] = es;
    __syncthreads();
    for (int off = 512; off; off >>= 1) {
        if (tid < off) fred[tid] += fred[tid + off];
        __syncthreads();
    }
    if (tid == 0) nOut[0] = 0.99f * fred[0] + OMD * (float)N_ROWS;
    __syncthreads();
    float L = lossPart[tid] + lossPart[tid + 1024] + lossPart[tid + 2048] + lossPart[tid + 3072];
    fred[tid] = L;
    __syncthreads();
    for (int off = 512; off; off >>= 1) {
        if (tid < off) fred[tid] += fred[tid + off];
        __syncthreads();
    }
    if (tid == 0) loss_out[0] = 1.25f * fred[0] / 4194304.0f;
}

// ---------------- merge: new_mean + new_codebook (streaming) ----------------
__global__ __launch_bounds__(256) void merge_kernel(const float* __restrict__ ema_mean,
                                                    const float* __restrict__ meanAcc,
                                                    const float* __restrict__ newCount,
                                                    const float* __restrict__ nPtr,
                                                    float* __restrict__ newMean_out,
                                                    float* __restrict__ newCb_out) {
    int g = blockIdx.x * 256 + threadIdx.x;
    int k = g >> 6;
    int c4 = (g & 63) * 4;
    float n = nPtr[0];
    float nc = newCount[k];
    float cs = (nc + 1e-5f) / (n + (float)(K_CODES * 1e-5)) * n;
    size_t base = (size_t)k * DIM + c4;
    float4 em = *(const float4*)(ema_mean + base);
    float4 mm = *(const float4*)(meanAcc + base);
    float4 nm;
    nm.x = 0.99f * em.x + 0.01f * mm.x;
    nm.y = 0.99f * em.y + 0.01f * mm.y;
    nm.z = 0.99f * em.z + 0.01f * mm.z;
    nm.w = 0.99f * em.w + 0.01f * mm.w;
    *(float4*)(newMean_out + base) = nm;
    float4 cbv;
    cbv.x = nm.x / cs;
    cbv.y = nm.y / cs;
    cbv.z = nm.z / cs;
    cbv.w = nm.w / cs;
    *(float4*)(newCb_out + base) = cbv;
}

extern "C" void kernel_launch(void* const* d_in, const int* in_sizes, int n_in,
                              void* d_out, int out_size, void* d_ws, size_t ws_size,
                              hipStream_t stream) {
    const float* z         = (const float*)d_in[0];
    const float* cb        = (const float*)d_in[1];
    const float* ema_count = (const float*)d_in[2];
    const float* ema_mean  = (const float*)d_in[3];
    float* out = (float*)d_out;
    char* ws = (char*)d_ws;

    unsigned* counts  = (unsigned*)(ws + WS_CNT);
    unsigned* cn8     = (unsigned*)(ws + WS_CN8);
    float* lossPart   = (float*)(ws + WS_LOSSP);
    float* nPtr       = (float*)(ws + WS_N);
    float* meanAcc    = (float*)(ws + WS_MEAN);

    signed char* zqp = (signed char*)(out + POFF_ZQP);
    signed char* cqp = (signed char*)(out + POFF_CQP);
    unsigned* cand  = (unsigned*)(out + POFF_CAND);

    prep_kernel<<<4097, 256, 0, stream>>>(z, cb, zqp, cqp, cn8, meanAcc, counts);
    dist_kernel<<<8192, 256, 0, stream>>>(zqp, cqp, cn8, cand);
    rescore_assign_kernel<<<N_ROWS / 4, 256, 0, stream>>>(z, cb, cand, out + OFF_ZQ,
                                                          out + OFF_IDX, counts, meanAcc,
                                                          lossPart);
    count_final_kernel<<<1, 1024, 0, stream>>>(counts, ema_count, lossPart,
                                               out + OFF_CNT, nPtr, out + OFF_LOSS);
    merge_kernel<<<(K_CODES * DIM / 4) / 256, 256, 0, stream>>>(ema_mean, meanAcc,
                                                                out + OFF_CNT, nPtr,
                                                                out + OFF_MEAN, out + OFF_CB);
}

// Round 18
// 114.892 us; speedup vs baseline: 1.3843x; 1.3843x over previous
//
#include <hip/hip_runtime.h>

// ---- problem constants ----
#define N_ROWS 16384   // 8*16*128
#define DIM    256
#define K_CODES 8192

// i8 quantization scale: max|N(0,1)| over 6.3M samples ~= 5.2 < 5.5
#define QSCALE (127.0f / 5.5f)

// output layout (flat float32, return order)
#define OFF_ZQ   0
#define OFF_LOSS 4194304
#define OFF_IDX  4194305
#define OFF_CB   4210689
#define OFF_CNT  6307841
#define OFF_MEAN 6316033

// d_out scratch (all consumed before the real outputs overwrite, stream-ordered):
//   zqp   [0 .. 1048576) floats       — permuted i8 z (4MB), dead after dist
//   cqp   [1048576 .. 1572864) floats — permuted i8 codebook (2MB), dead after dist
//   cand  [4210692 .. 5259268) floats — u32[16384][64] keys, dead after rescore
//   brows/bcode alias cand region post-rescore; consumed by bucket_sum BEFORE
//   merge overwrites the CB region (stream-ordered)
#define POFF_ZQP   0
#define POFF_CQP   1048576
#define POFF_CAND  4210692
#define POFF_BROWS 4210692
#define POFF_BCODE 4227076

// workspace layout (bytes) — fits R1-proven 8.65MB footprint
#define WS_CNT    0        // u32[8192]   -> 32768
#define WS_CN8    32768    // u32[8192]   -> 65536  (biased<<7 codebook norms)
#define WS_LOSSP  65536    // f32[4096]   -> 81920
#define WS_N      81920    // f32         -> 81924
#define WS_MEAN   98304    // f32[8192*256] -> 8486912
#define WS_CUR    8486912  // u32[8192]   -> 8519680
#define WS_ROWC   8519680  // u32[16384]  -> 8585216 (< 8650752 proven)

typedef int i32x4 __attribute__((ext_vector_type(4)));
typedef float f32x4 __attribute__((ext_vector_type(4)));

__device__ inline signed char q8(float v) {
    float x = v * QSCALE;
    x = fminf(fmaxf(x, -127.0f), 127.0f);
    return (signed char)__float2int_rn(x);
}

// ---------------- prep: quantize z + cb to permuted i8 planes + biased cnorm + zero meanAcc/counts ----------------
// zqp bytes: [zblk(128)][kc(4)][gk(4)][r(128)][16 i8]
// cqp bytes: [cblk(32)][kc(4)][gk(4)][r(256)][16 i8]
__global__ __launch_bounds__(256) void prep_kernel(const float* __restrict__ z,
                                                   const float* __restrict__ cb,
                                                   signed char* __restrict__ zqp,
                                                   signed char* __restrict__ cqp,
                                                   unsigned* __restrict__ cn8,
                                                   float* __restrict__ meanAcc,
                                                   unsigned* __restrict__ counts) {
    int b = blockIdx.x;
    if (b < 1024) {                       // ---- z quantize: one 16-elem granule per thread
        int g = b * 256 + threadIdx.x;
        int row = g >> 4, gr = g & 15;
        const float* src = z + (size_t)row * DIM + gr * 16;
        char cq[16];
        #pragma unroll
        for (int t = 0; t < 4; ++t) {
            float4 v = *(const float4*)(src + t * 4);
            cq[t * 4 + 0] = q8(v.x); cq[t * 4 + 1] = q8(v.y);
            cq[t * 4 + 2] = q8(v.z); cq[t * 4 + 3] = q8(v.w);
        }
        int zblk = row >> 7, r = row & 127, kc = gr >> 2, gk = gr & 3;
        size_t o = ((size_t)((zblk * 4 + kc) * 4 + gk) * 128 + r) * 16;
        *(i32x4*)(zqp + o) = *(const i32x4*)cq;
    } else if (b < 3072) {                // ---- cb quantize + biased int cnorm: one wave per row
        int w = threadIdx.x >> 6, lane = threadIdx.x & 63;
        int row = (b - 1024) * 4 + w;
        float4 v = *(const float4*)(cb + (size_t)row * DIM + lane * 4);
        char cq[4] = {q8(v.x), q8(v.y), q8(v.z), q8(v.w)};
        int gr = lane >> 2;               // granule 0..15
        int kc = gr >> 2, gk = gr & 3;
        int cblk = row >> 8, r = row & 255;
        size_t o = ((size_t)((cblk * 4 + kc) * 4 + gk) * 256 + r) * 16 + (lane & 3) * 4;
        *(int*)(cqp + o) = *(const int*)cq;
        int s = (int)cq[0] * cq[0] + (int)cq[1] * cq[1] + (int)cq[2] * cq[2] + (int)cq[3] * cq[3];
        #pragma unroll
        for (int off = 32; off; off >>= 1) s += __shfl_down(s, off, 64);
        if (lane == 0) cn8[row] = ((unsigned)(s + 16777216)) << 7;   // (cnorm + 2^24) << 7
    } else if (b < 4096) {                // ---- zero meanAcc: 8 floats per thread
        int g = (b - 3072) * 256 + threadIdx.x;
        float4 zero = {0.f, 0.f, 0.f, 0.f};
        float4* p = (float4*)(meanAcc + (size_t)g * 8);
        p[0] = zero; p[1] = zero;
    } else {                              // ---- zero counts (b == 4096)
        #pragma unroll
        for (int i = 0; i < 32; ++i) counts[threadIdx.x * 32 + i] = 0u;
    }
}

// ---------------- distance screen: i8 MFMA, pinned 2-deep prefetch, 3-op keys ----------------
// block = 256 codes x 64 z, 4 waves; wave = 64 codes x 64 z (4i x 4j of 16x16x64_i8, 4 kc).
// R9-proven read swizzle; R11-proven sched_barrier prefetch pin.
// 2-deep rotation (3 slot sets, hand-unrolled kc=0..3): per-kc MFMA phase (~75cy)
// < L2 latency (~200cy), so 1-deep exposed ~125cy/iter; 2-deep covers it.
// launch_bounds (256,2) RAISES the VGPR cap (R15 lesson: never cap below the
// pipeline's register need); actual residency was already 2 blocks/CU.
// key = ((cn8 - (acc<<8)) & 0xFFFFFF00) | id  ==  (((cn-2acc)+2^24)>>1)<<8 | id  (exact)
__global__ __launch_bounds__(256, 2) void dist_kernel(const signed char* __restrict__ zqp,
                                                      const signed char* __restrict__ cqp,
                                                      const unsigned* __restrict__ cn8,
                                                      unsigned* __restrict__ cand) {
    __shared__ unsigned red[4][64][2];

    const int tid = threadIdx.x;
    const int w = tid >> 6, lane = tid & 63;
    const int c16 = lane & 15, g4 = lane >> 4;

    int b = blockIdx.x;
    int xcd = b & 7;
    int wgx = b >> 3;
    int cbY = wgx >> 5;              // slow: code block (256 codes)
    int zbX = xcd * 32 + (wgx & 31); // fast: z block (64 rows), XCD-contiguous

    i32x4 acc[4][4];
    #pragma unroll
    for (int i = 0; i < 4; ++i)
        #pragma unroll
        for (int j = 0; j < 4; ++j) acc[i][j] = 0;

    const signed char* Abase = cqp + (size_t)cbY * 65536 + g4 * 4096 + (w * 64 + c16) * 16;
    const signed char* Bbase = zqp + (size_t)(zbX >> 1) * 32768 + g4 * 2048 + ((zbX & 1) * 64 + c16) * 16;

    // 3 slot sets: A (kc0, reused for kc3), B (kc1), C (kc2)
    i32x4 aA[4], bA[4], aB[4], bB[4], aC[4], bC[4];
    #pragma unroll
    for (int i = 0; i < 4; ++i) aA[i] = *(const i32x4*)(Abase + i * 256);
    #pragma unroll
    for (int j = 0; j < 4; ++j) bA[j] = *(const i32x4*)(Bbase + j * 256);
    #pragma unroll
    for (int i = 0; i < 4; ++i) aB[i] = *(const i32x4*)(Abase + 16384 + i * 256);
    #pragma unroll
    for (int j = 0; j < 4; ++j) bB[j] = *(const i32x4*)(Bbase + 8192 + j * 256);

    // kc = 0: issue kc2 loads, compute with A
    #pragma unroll
    for (int i = 0; i < 4; ++i) aC[i] = *(const i32x4*)(Abase + 2 * 16384 + i * 256);
    #pragma unroll
    for (int j = 0; j < 4; ++j) bC[j] = *(const i32x4*)(Bbase + 2 * 8192 + j * 256);
    __builtin_amdgcn_sched_barrier(0);
    #pragma unroll
    for (int i = 0; i < 4; ++i)
        #pragma unroll
        for (int j = 0; j < 4; ++j)
            acc[i][j] = __builtin_amdgcn_mfma_i32_16x16x64_i8(aA[i], bA[j], acc[i][j], 0, 0, 0);
    __builtin_amdgcn_sched_barrier(0);

    // kc = 1: issue kc3 loads into A (consumed at kc0), compute with B
    #pragma unroll
    for (int i = 0; i < 4; ++i) aA[i] = *(const i32x4*)(Abase + 3 * 16384 + i * 256);
    #pragma unroll
    for (int j = 0; j < 4; ++j) bA[j] = *(const i32x4*)(Bbase + 3 * 8192 + j * 256);
    __builtin_amdgcn_sched_barrier(0);
    #pragma unroll
    for (int i = 0; i < 4; ++i)
        #pragma unroll
        for (int j = 0; j < 4; ++j)
            acc[i][j] = __builtin_amdgcn_mfma_i32_16x16x64_i8(aB[i], bB[j], acc[i][j], 0, 0, 0);
    __builtin_amdgcn_sched_barrier(0);

    // kc = 2: compute with C
    #pragma unroll
    for (int i = 0; i < 4; ++i)
        #pragma unroll
        for (int j = 0; j < 4; ++j)
            acc[i][j] = __builtin_amdgcn_mfma_i32_16x16x64_i8(aC[i], bC[j], acc[i][j], 0, 0, 0);

    // kc = 3: compute with A (second use)
    #pragma unroll
    for (int i = 0; i < 4; ++i)
        #pragma unroll
        for (int j = 0; j < 4; ++j)
            acc[i][j] = __builtin_amdgcn_mfma_i32_16x16x64_i8(aA[i], bA[j], acc[i][j], 0, 0, 0);

    unsigned cn[4][4];
    #pragma unroll
    for (int i = 0; i < 4; ++i)
        #pragma unroll
        for (int reg = 0; reg < 4; ++reg)
            cn[i][reg] = cn8[cbY * 256 + w * 64 + i * 16 + g4 * 4 + reg];

    // epilogue: top-2 per (z-col, 256-code block); C/D: col=lane&15 (z), row=(lane>>4)*4+reg
    #pragma unroll
    for (int j = 0; j < 4; ++j) {
        unsigned b1 = 0xFFFFFFFFu, b2 = 0xFFFFFFFFu;
        #pragma unroll
        for (int i = 0; i < 4; ++i) {
            #pragma unroll
            for (int reg = 0; reg < 4; ++reg) {
                unsigned id = (unsigned)(w * 64 + i * 16 + g4 * 4 + reg);
                unsigned key = ((cn[i][reg] - ((unsigned)acc[i][j][reg] << 8)) & 0xFFFFFF00u) | id;
                unsigned mx = max(b1, key);
                b1 = min(b1, key);
                b2 = min(b2, mx);
            }
        }
        #pragma unroll
        for (int off = 16; off <= 32; off <<= 1) {
            unsigned o1 = __shfl_xor(b1, off), o2 = __shfl_xor(b2, off);
            unsigned m1 = min(b1, o1);
            unsigned hi = max(b1, o1);
            b1 = m1;
            b2 = min(min(b2, o2), hi);
        }
        if (lane < 16) { red[w][j * 16 + lane][0] = b1; red[w][j * 16 + lane][1] = b2; }
    }
    __syncthreads();
    if (tid < 64) {
        unsigned b1 = 0xFFFFFFFFu, b2 = 0xFFFFFFFFu;
        #pragma unroll
        for (int t = 0; t < 4; ++t) {
            unsigned o1 = red[t][tid][0], o2 = red[t][tid][1];
            unsigned m1 = min(b1, o1);
            unsigned hi = max(b1, o1);
            b1 = m1;
            b2 = min(min(b2, o2), hi);
        }
        size_t base = (size_t)(zbX * 64 + tid) * 64 + cbY * 2;   // row-major
        *(uint2*)(cand + base) = make_uint2(b1, b2);
    }
}

// ---------------- rescore (fp64 within margin): idx, rowcode, counts, zq, loss ----------------
// NO direct meanAcc atomics: R17 re-proved hot-code same-address serialization
// costs ~87us (Gumbel skew -> a few codes win 1000s of rows). Bucket path instead.
__global__ __launch_bounds__(256) void rescore_kernel(const float* __restrict__ z,
                                                      const float* __restrict__ cb,
                                                      const unsigned* __restrict__ cand,
                                                      float* __restrict__ zq_out,
                                                      float* __restrict__ idx_out,
                                                      unsigned* __restrict__ rowcode,
                                                      unsigned* __restrict__ counts,
                                                      float* __restrict__ lossPart) {
    __shared__ float lred[4];
    int w = threadIdx.x >> 6, lane = threadIdx.x & 63;
    int row = blockIdx.x * 4 + w;
    unsigned k32 = cand[(size_t)row * 64 + lane];   // coalesced row-major gather
    unsigned m = k32;
    #pragma unroll
    for (int off = 32; off; off >>= 1) {
        unsigned o = __shfl_xor(m, off);
        if (o < m) m = o;
    }
    // margin: 5.25 real / (5.5/127)^2 = 2800 d-units = 1400 half-units (key>>8 domain)
    unsigned vmin = m >> 8;
    unsigned vme = k32 >> 8;
    int mycode = (lane >> 1) * 256 + (int)(k32 & 0xFFu);
    unsigned long long mask = __ballot(vme <= vmin + 1400u);

    float4 zv = *(const float4*)(z + (size_t)row * DIM + lane * 4);
    double bd = 1e300;
    int bc = 0x7fffffff;
    while (mask) {
        int src = __ffsll((unsigned long long)mask) - 1;
        mask &= mask - 1;
        int code = __shfl(mycode, src);
        float4 c4 = *(const float4*)(cb + (size_t)code * DIM + lane * 4);
        double d0 = (double)zv.x - c4.x, d1 = (double)zv.y - c4.y;
        double d2 = (double)zv.z - c4.z, d3 = (double)zv.w - c4.w;
        double s = d0 * d0 + d1 * d1 + d2 * d2 + d3 * d3;
        #pragma unroll
        for (int off = 32; off; off >>= 1) s += __shfl_xor(s, off);
        if (s < bd || (s == bd && code < bc)) { bd = s; bc = code; }
    }

    float4 cv = *(const float4*)(cb + (size_t)bc * DIM + lane * 4);
    *(float4*)(zq_out + (size_t)row * DIM + lane * 4) = cv;
    if (lane == 0) {
        idx_out[row] = (float)bc;
        rowcode[row] = (unsigned)bc;
        atomicAdd(counts + bc, 1u);
        lred[w] = (float)bd;
    }
    __syncthreads();
    if (threadIdx.x == 0)
        lossPart[blockIdx.x] = lred[0] + lred[1] + lred[2] + lred[3];
}

// ---------------- prefix: cursor + newCount + n + loss (single block) ----------------
__global__ __launch_bounds__(1024) void prefix_kernel(const unsigned* __restrict__ counts,
                                                      const float* __restrict__ ema_count,
                                                      const float* __restrict__ lossPart,
                                                      unsigned* __restrict__ cursor,
                                                      float* __restrict__ newCount_out,
                                                      float* __restrict__ nOut,
                                                      float* __restrict__ loss_out) {
    __shared__ unsigned ssum[1024];
    __shared__ float fred[1024];
    const float OMD = 0.01f;
    int tid = threadIdx.x;
    int base = tid * 8;

    unsigned v[8];
    unsigned s = 0;
    float es = 0.f;
    #pragma unroll
    for (int i = 0; i < 8; ++i) {
        v[i] = counts[base + i];
        s += v[i];
        float e = ema_count[base + i];
        es += e;
        newCount_out[base + i] = 0.99f * e + OMD * (float)v[i];
    }
    ssum[tid] = s;
    __syncthreads();
    for (int off = 1; off < 1024; off <<= 1) {
        unsigned t = (tid >= off) ? ssum[tid - off] : 0u;
        __syncthreads();
        ssum[tid] += t;
        __syncthreads();
    }
    unsigned run = ssum[tid] - s;   // exclusive prefix
    #pragma unroll
    for (int i = 0; i < 8; ++i) {
        cursor[base + i] = run;
        run += v[i];
    }

    fred[tid] = es;
    __syncthreads();
    for (int off = 512; off; off >>= 1) {
        if (tid < off) fred[tid] += fred[tid + off];
        __syncthreads();
    }
    if (tid == 0) nOut[0] = 0.99f * fred[0] + OMD * (float)N_ROWS;
    __syncthreads();
    float L = lossPart[tid] + lossPart[tid + 1024] + lossPart[tid + 2048] + lossPart[tid + 3072];
    fred[tid] = L;
    __syncthreads();
    for (int off = 512; off; off >>= 1) {
        if (tid < off) fred[tid] += fred[tid + off];
        __syncthreads();
    }
    if (tid == 0) loss_out[0] = 1.25f * fred[0] / 4194304.0f;
}

// ---------------- scatter rows into code-sorted bucket list ----------------
__global__ __launch_bounds__(256) void scatter_kernel(const unsigned* __restrict__ rowcode,
                                                      unsigned* __restrict__ cursor,
                                                      unsigned* __restrict__ bucketRows,
                                                      unsigned* __restrict__ bucketCodes) {
    int row = blockIdx.x * 256 + threadIdx.x;
    unsigned code = rowcode[row];
    unsigned pos = atomicAdd(cursor + code, 1u);
    bucketRows[pos] = row;
    bucketCodes[pos] = code;
}

// ---------------- bucket_sum: work-balanced segmented reduction over entries ----------------
__global__ __launch_bounds__(256) void bucket_sum_kernel(const float* __restrict__ z,
                                                         const unsigned* __restrict__ bucketRows,
                                                         const unsigned* __restrict__ bucketCodes,
                                                         float* __restrict__ meanAcc) {
    int w = threadIdx.x >> 6, lane = threadIdx.x & 63;
    int base = (blockIdx.x * 4 + w) * 8;

    float4 acc = {0.f, 0.f, 0.f, 0.f};
    unsigned cur = bucketCodes[base];
    #pragma unroll
    for (int e = 0; e < 8; ++e) {
        int p = base + e;
        unsigned code = bucketCodes[p];
        if (code != cur) {
            float* mp = meanAcc + (size_t)cur * DIM + lane * 4;
            atomicAdd(mp + 0, acc.x);
            atomicAdd(mp + 1, acc.y);
            atomicAdd(mp + 2, acc.z);
            atomicAdd(mp + 3, acc.w);
            acc.x = acc.y = acc.z = acc.w = 0.f;
            cur = code;
        }
        unsigned r = bucketRows[p];
        float4 zv = *(const float4*)(z + (size_t)r * DIM + lane * 4);
        acc.x += zv.x; acc.y += zv.y; acc.z += zv.z; acc.w += zv.w;
    }
    float* mp = meanAcc + (size_t)cur * DIM + lane * 4;
    atomicAdd(mp + 0, acc.x);
    atomicAdd(mp + 1, acc.y);
    atomicAdd(mp + 2, acc.z);
    atomicAdd(mp + 3, acc.w);
}

// ---------------- merge: new_mean + new_codebook (streaming) ----------------
__global__ __launch_bounds__(256) void merge_kernel(const float* __restrict__ ema_mean,
                                                    const float* __restrict__ meanAcc,
                                                    const float* __restrict__ newCount,
                                                    const float* __restrict__ nPtr,
                                                    float* __restrict__ newMean_out,
                                                    float* __restrict__ newCb_out) {
    int g = blockIdx.x * 256 + threadIdx.x;
    int k = g >> 6;
    int c4 = (g & 63) * 4;
    float n = nPtr[0];
    float nc = newCount[k];
    float cs = (nc + 1e-5f) / (n + (float)(K_CODES * 1e-5)) * n;
    size_t base = (size_t)k * DIM + c4;
    float4 em = *(const float4*)(ema_mean + base);
    float4 mm = *(const float4*)(meanAcc + base);
    float4 nm;
    nm.x = 0.99f * em.x + 0.01f * mm.x;
    nm.y = 0.99f * em.y + 0.01f * mm.y;
    nm.z = 0.99f * em.z + 0.01f * mm.z;
    nm.w = 0.99f * em.w + 0.01f * mm.w;
    *(float4*)(newMean_out + base) = nm;
    float4 cbv;
    cbv.x = nm.x / cs;
    cbv.y = nm.y / cs;
    cbv.z = nm.z / cs;
    cbv.w = nm.w / cs;
    *(float4*)(newCb_out + base) = cbv;
}

extern "C" void kernel_launch(void* const* d_in, const int* in_sizes, int n_in,
                              void* d_out, int out_size, void* d_ws, size_t ws_size,
                              hipStream_t stream) {
    const float* z         = (const float*)d_in[0];
    const float* cb        = (const float*)d_in[1];
    const float* ema_count = (const float*)d_in[2];
    const float* ema_mean  = (const float*)d_in[3];
    float* out = (float*)d_out;
    char* ws = (char*)d_ws;

    unsigned* counts  = (unsigned*)(ws + WS_CNT);
    unsigned* cn8     = (unsigned*)(ws + WS_CN8);
    float* lossPart   = (float*)(ws + WS_LOSSP);
    float* nPtr       = (float*)(ws + WS_N);
    float* meanAcc    = (float*)(ws + WS_MEAN);
    unsigned* cursor  = (unsigned*)(ws + WS_CUR);
    unsigned* rowcode = (unsigned*)(ws + WS_ROWC);

    signed char* zqp = (signed char*)(out + POFF_ZQP);
    signed char* cqp = (signed char*)(out + POFF_CQP);
    unsigned* cand  = (unsigned*)(out + POFF_CAND);
    unsigned* brows = (unsigned*)(out + POFF_BROWS);   // aliases cand: used post-rescore
    unsigned* bcode = (unsigned*)(out + POFF_BCODE);

    prep_kernel<<<4097, 256, 0, stream>>>(z, cb, zqp, cqp, cn8, meanAcc, counts);
    dist_kernel<<<8192, 256, 0, stream>>>(zqp, cqp, cn8, cand);
    rescore_kernel<<<N_ROWS / 4, 256, 0, stream>>>(z, cb, cand, out + OFF_ZQ, out + OFF_IDX,
                                                   rowcode, counts, lossPart);
    prefix_kernel<<<1, 1024, 0, stream>>>(counts, ema_count, lossPart, cursor,
                                          out + OFF_CNT, nPtr, out + OFF_LOSS);
    scatter_kernel<<<N_ROWS / 256, 256, 0, stream>>>(rowcode, cursor, brows, bcode);
    bucket_sum_kernel<<<512, 256, 0, stream>>>(z, brows, bcode, meanAcc);
    merge_kernel<<<(K_CODES * DIM / 4) / 256, 256, 0, stream>>>(ema_mean, meanAcc,
                                                                out + OFF_CNT, nPtr,
                                                                out + OFF_MEAN, out + OFF_CB);
}

// Round 19
// 113.152 us; speedup vs baseline: 1.4056x; 1.0154x over previous
//
#include <hip/hip_runtime.h>

// ---- problem constants ----
#define N_ROWS 16384   // 8*16*128
#define DIM    256
#define K_CODES 8192

// i8 quantization scale: max|N(0,1)| over 6.3M samples ~= 5.2 < 5.5
#define QSCALE (127.0f / 5.5f)

// output layout (flat float32, return order)
#define OFF_ZQ   0
#define OFF_LOSS 4194304
#define OFF_IDX  4194305
#define OFF_CB   4210689
#define OFF_CNT  6307841
#define OFF_MEAN 6316033

// d_out scratch (all consumed before the real outputs overwrite, stream-ordered):
//   zqp   [0 .. 1048576) floats       — permuted i8 z (4MB), dead after dist
//   cqp   [1048576 .. 1572864) floats — permuted i8 codebook (2MB), dead after dist
//   cand  [4210692 .. 5259268) floats — u32[16384][64] keys, dead after rescore
//   brows/bcode alias cand region post-rescore; consumed by bucket_sum BEFORE
//   merge overwrites the CB region (stream-ordered)
#define POFF_ZQP   0
#define POFF_CQP   1048576
#define POFF_CAND  4210692
#define POFF_BROWS 4210692
#define POFF_BCODE 4227076

// workspace layout (bytes) — fits R1-proven 8.65MB footprint
#define WS_CNT    0        // u32[8192]   -> 32768
#define WS_CN8    32768    // u32[8192]   -> 65536  (biased<<7 codebook norms)
#define WS_LOSSP  65536    // f32[4096]   -> 81920
#define WS_N      81920    // f32         -> 81924
#define WS_MEAN   98304    // f32[8192*256] -> 8486912
#define WS_CUR    8486912  // u32[8192]   -> 8519680
#define WS_ROWC   8519680  // u32[16384]  -> 8585216 (< 8650752 proven)

typedef int i32x4 __attribute__((ext_vector_type(4)));
typedef float f32x4 __attribute__((ext_vector_type(4)));

__device__ inline signed char q8(float v) {
    float x = v * QSCALE;
    x = fminf(fmaxf(x, -127.0f), 127.0f);
    return (signed char)__float2int_rn(x);
}

// ---------------- prep: quantize z + cb to permuted i8 planes + biased cnorm + zero meanAcc/counts ----------------
// zqp bytes: [zblk(128)][kc(4)][gk(4)][r(128)][16 i8]
// cqp bytes: [cblk(32)][kc(4)][gk(4)][r(256)][16 i8]
__global__ __launch_bounds__(256) void prep_kernel(const float* __restrict__ z,
                                                   const float* __restrict__ cb,
                                                   signed char* __restrict__ zqp,
                                                   signed char* __restrict__ cqp,
                                                   unsigned* __restrict__ cn8,
                                                   float* __restrict__ meanAcc,
                                                   unsigned* __restrict__ counts) {
    int b = blockIdx.x;
    if (b < 1024) {                       // ---- z quantize: one 16-elem granule per thread
        int g = b * 256 + threadIdx.x;
        int row = g >> 4, gr = g & 15;
        const float* src = z + (size_t)row * DIM + gr * 16;
        char cq[16];
        #pragma unroll
        for (int t = 0; t < 4; ++t) {
            float4 v = *(const float4*)(src + t * 4);
            cq[t * 4 + 0] = q8(v.x); cq[t * 4 + 1] = q8(v.y);
            cq[t * 4 + 2] = q8(v.z); cq[t * 4 + 3] = q8(v.w);
        }
        int zblk = row >> 7, r = row & 127, kc = gr >> 2, gk = gr & 3;
        size_t o = ((size_t)((zblk * 4 + kc) * 4 + gk) * 128 + r) * 16;
        *(i32x4*)(zqp + o) = *(const i32x4*)cq;
    } else if (b < 3072) {                // ---- cb quantize + biased int cnorm: one wave per row
        int w = threadIdx.x >> 6, lane = threadIdx.x & 63;
        int row = (b - 1024) * 4 + w;
        float4 v = *(const float4*)(cb + (size_t)row * DIM + lane * 4);
        char cq[4] = {q8(v.x), q8(v.y), q8(v.z), q8(v.w)};
        int gr = lane >> 2;               // granule 0..15
        int kc = gr >> 2, gk = gr & 3;
        int cblk = row >> 8, r = row & 255;
        size_t o = ((size_t)((cblk * 4 + kc) * 4 + gk) * 256 + r) * 16 + (lane & 3) * 4;
        *(int*)(cqp + o) = *(const int*)cq;
        int s = (int)cq[0] * cq[0] + (int)cq[1] * cq[1] + (int)cq[2] * cq[2] + (int)cq[3] * cq[3];
        #pragma unroll
        for (int off = 32; off; off >>= 1) s += __shfl_down(s, off, 64);
        if (lane == 0) cn8[row] = ((unsigned)(s + 16777216)) << 7;   // (cnorm + 2^24) << 7
    } else if (b < 4096) {                // ---- zero meanAcc: 8 floats per thread
        int g = (b - 3072) * 256 + threadIdx.x;
        float4 zero = {0.f, 0.f, 0.f, 0.f};
        float4* p = (float4*)(meanAcc + (size_t)g * 8);
        p[0] = zero; p[1] = zero;
    } else {                              // ---- zero counts (b == 4096)
        #pragma unroll
        for (int i = 0; i < 32; ++i) counts[threadIdx.x * 32 + i] = 0u;
    }
}

// ---------------- distance screen: i8 MFMA, pinned 2-deep prefetch, 3-op keys ----------------
// block = 256 codes x 64 z, 4 waves; wave = 64 codes x 64 z (4i x 4j of 16x16x64_i8, 4 kc).
// R9-proven read swizzle; R11-proven sched_barrier prefetch pin; R18 2-deep rotation.
// launch_bounds (256,2) RAISES the VGPR cap (R15 lesson: never cap below the
// pipeline's register need); actual residency was already 2 blocks/CU.
// key = ((cn8 - (acc<<8)) & 0xFFFFFF00) | id  ==  (((cn-2acc)+2^24)>>1)<<8 | id  (exact)
__global__ __launch_bounds__(256, 2) void dist_kernel(const signed char* __restrict__ zqp,
                                                      const signed char* __restrict__ cqp,
                                                      const unsigned* __restrict__ cn8,
                                                      unsigned* __restrict__ cand) {
    __shared__ unsigned red[4][64][2];

    const int tid = threadIdx.x;
    const int w = tid >> 6, lane = tid & 63;
    const int c16 = lane & 15, g4 = lane >> 4;

    int b = blockIdx.x;
    int xcd = b & 7;
    int wgx = b >> 3;
    int cbY = wgx >> 5;              // slow: code block (256 codes)
    int zbX = xcd * 32 + (wgx & 31); // fast: z block (64 rows), XCD-contiguous

    i32x4 acc[4][4];
    #pragma unroll
    for (int i = 0; i < 4; ++i)
        #pragma unroll
        for (int j = 0; j < 4; ++j) acc[i][j] = 0;

    const signed char* Abase = cqp + (size_t)cbY * 65536 + g4 * 4096 + (w * 64 + c16) * 16;
    const signed char* Bbase = zqp + (size_t)(zbX >> 1) * 32768 + g4 * 2048 + ((zbX & 1) * 64 + c16) * 16;

    // 3 slot sets: A (kc0, reused for kc3), B (kc1), C (kc2)
    i32x4 aA[4], bA[4], aB[4], bB[4], aC[4], bC[4];
    #pragma unroll
    for (int i = 0; i < 4; ++i) aA[i] = *(const i32x4*)(Abase + i * 256);
    #pragma unroll
    for (int j = 0; j < 4; ++j) bA[j] = *(const i32x4*)(Bbase + j * 256);
    #pragma unroll
    for (int i = 0; i < 4; ++i) aB[i] = *(const i32x4*)(Abase + 16384 + i * 256);
    #pragma unroll
    for (int j = 0; j < 4; ++j) bB[j] = *(const i32x4*)(Bbase + 8192 + j * 256);

    // kc = 0: issue kc2 loads, compute with A
    #pragma unroll
    for (int i = 0; i < 4; ++i) aC[i] = *(const i32x4*)(Abase + 2 * 16384 + i * 256);
    #pragma unroll
    for (int j = 0; j < 4; ++j) bC[j] = *(const i32x4*)(Bbase + 2 * 8192 + j * 256);
    __builtin_amdgcn_sched_barrier(0);
    #pragma unroll
    for (int i = 0; i < 4; ++i)
        #pragma unroll
        for (int j = 0; j < 4; ++j)
            acc[i][j] = __builtin_amdgcn_mfma_i32_16x16x64_i8(aA[i], bA[j], acc[i][j], 0, 0, 0);
    __builtin_amdgcn_sched_barrier(0);

    // kc = 1: issue kc3 loads into A (consumed at kc3), compute with B
    #pragma unroll
    for (int i = 0; i < 4; ++i) aA[i] = *(const i32x4*)(Abase + 3 * 16384 + i * 256);
    #pragma unroll
    for (int j = 0; j < 4; ++j) bA[j] = *(const i32x4*)(Bbase + 3 * 8192 + j * 256);
    __builtin_amdgcn_sched_barrier(0);
    #pragma unroll
    for (int i = 0; i < 4; ++i)
        #pragma unroll
        for (int j = 0; j < 4; ++j)
            acc[i][j] = __builtin_amdgcn_mfma_i32_16x16x64_i8(aB[i], bB[j], acc[i][j], 0, 0, 0);
    __builtin_amdgcn_sched_barrier(0);

    // kc = 2: compute with C
    #pragma unroll
    for (int i = 0; i < 4; ++i)
        #pragma unroll
        for (int j = 0; j < 4; ++j)
            acc[i][j] = __builtin_amdgcn_mfma_i32_16x16x64_i8(aC[i], bC[j], acc[i][j], 0, 0, 0);

    // kc = 3: compute with A (second use)
    #pragma unroll
    for (int i = 0; i < 4; ++i)
        #pragma unroll
        for (int j = 0; j < 4; ++j)
            acc[i][j] = __builtin_amdgcn_mfma_i32_16x16x64_i8(aA[i], bA[j], acc[i][j], 0, 0, 0);

    unsigned cn[4][4];
    #pragma unroll
    for (int i = 0; i < 4; ++i)
        #pragma unroll
        for (int reg = 0; reg < 4; ++reg)
            cn[i][reg] = cn8[cbY * 256 + w * 64 + i * 16 + g4 * 4 + reg];

    // epilogue: top-2 per (z-col, 256-code block); C/D: col=lane&15 (z), row=(lane>>4)*4+reg
    #pragma unroll
    for (int j = 0; j < 4; ++j) {
        unsigned b1 = 0xFFFFFFFFu, b2 = 0xFFFFFFFFu;
        #pragma unroll
        for (int i = 0; i < 4; ++i) {
            #pragma unroll
            for (int reg = 0; reg < 4; ++reg) {
                unsigned id = (unsigned)(w * 64 + i * 16 + g4 * 4 + reg);
                unsigned key = ((cn[i][reg] - ((unsigned)acc[i][j][reg] << 8)) & 0xFFFFFF00u) | id;
                unsigned mx = max(b1, key);
                b1 = min(b1, key);
                b2 = min(b2, mx);
            }
        }
        #pragma unroll
        for (int off = 16; off <= 32; off <<= 1) {
            unsigned o1 = __shfl_xor(b1, off), o2 = __shfl_xor(b2, off);
            unsigned m1 = min(b1, o1);
            unsigned hi = max(b1, o1);
            b1 = m1;
            b2 = min(min(b2, o2), hi);
        }
        if (lane < 16) { red[w][j * 16 + lane][0] = b1; red[w][j * 16 + lane][1] = b2; }
    }
    __syncthreads();
    if (tid < 64) {
        unsigned b1 = 0xFFFFFFFFu, b2 = 0xFFFFFFFFu;
        #pragma unroll
        for (int t = 0; t < 4; ++t) {
            unsigned o1 = red[t][tid][0], o2 = red[t][tid][1];
            unsigned m1 = min(b1, o1);
            unsigned hi = max(b1, o1);
            b1 = m1;
            b2 = min(min(b2, o2), hi);
        }
        size_t base = (size_t)(zbX * 64 + tid) * 64 + cbY * 2;   // row-major
        *(uint2*)(cand + base) = make_uint2(b1, b2);
    }
}

// ---------------- rescore (fp64 within margin): idx, rowcode, counts, zq, loss ----------------
// NO direct meanAcc atomics: R17 re-proved hot-code same-address serialization
// costs ~87us (Gumbel skew -> a few codes win 1000s of rows). Bucket path instead.
__global__ __launch_bounds__(256) void rescore_kernel(const float* __restrict__ z,
                                                      const float* __restrict__ cb,
                                                      const unsigned* __restrict__ cand,
                                                      float* __restrict__ zq_out,
                                                      float* __restrict__ idx_out,
                                                      unsigned* __restrict__ rowcode,
                                                      unsigned* __restrict__ counts,
                                                      float* __restrict__ lossPart) {
    __shared__ float lred[4];
    int w = threadIdx.x >> 6, lane = threadIdx.x & 63;
    int row = blockIdx.x * 4 + w;
    unsigned k32 = cand[(size_t)row * 64 + lane];   // coalesced row-major gather
    unsigned m = k32;
    #pragma unroll
    for (int off = 32; off; off >>= 1) {
        unsigned o = __shfl_xor(m, off);
        if (o < m) m = o;
    }
    // margin: 5.25 real / (5.5/127)^2 = 2800 d-units = 1400 half-units (key>>8 domain)
    unsigned vmin = m >> 8;
    unsigned vme = k32 >> 8;
    int mycode = (lane >> 1) * 256 + (int)(k32 & 0xFFu);
    unsigned long long mask = __ballot(vme <= vmin + 1400u);

    float4 zv = *(const float4*)(z + (size_t)row * DIM + lane * 4);
    double bd = 1e300;
    int bc = 0x7fffffff;
    while (mask) {
        int src = __ffsll((unsigned long long)mask) - 1;
        mask &= mask - 1;
        int code = __shfl(mycode, src);
        float4 c4 = *(const float4*)(cb + (size_t)code * DIM + lane * 4);
        double d0 = (double)zv.x - c4.x, d1 = (double)zv.y - c4.y;
        double d2 = (double)zv.z - c4.z, d3 = (double)zv.w - c4.w;
        double s = d0 * d0 + d1 * d1 + d2 * d2 + d3 * d3;
        #pragma unroll
        for (int off = 32; off; off >>= 1) s += __shfl_xor(s, off);
        if (s < bd || (s == bd && code < bc)) { bd = s; bc = code; }
    }

    float4 cv = *(const float4*)(cb + (size_t)bc * DIM + lane * 4);
    *(float4*)(zq_out + (size_t)row * DIM + lane * 4) = cv;
    if (lane == 0) {
        idx_out[row] = (float)bc;
        rowcode[row] = (unsigned)bc;
        atomicAdd(counts + bc, 1u);
        lred[w] = (float)bd;
    }
    __syncthreads();
    if (threadIdx.x == 0)
        lossPart[blockIdx.x] = lred[0] + lred[1] + lred[2] + lred[3];
}

// ---------------- prefix: cursor + newCount + n + loss — wave-shfl scan, 2 barriers ----------------
// R18's Hillis-Steele version had ~26 barriers with 16 waves on one CU (~10us).
// Wave-synchronous shfl scans/reductions need none; only 2 cross-wave barriers remain.
__global__ __launch_bounds__(1024) void prefix_kernel(const unsigned* __restrict__ counts,
                                                      const float* __restrict__ ema_count,
                                                      const float* __restrict__ lossPart,
                                                      unsigned* __restrict__ cursor,
                                                      float* __restrict__ newCount_out,
                                                      float* __restrict__ nOut,
                                                      float* __restrict__ loss_out) {
    __shared__ unsigned wsum[16];
    __shared__ float wes[16], wls[16];
    const float OMD = 0.01f;
    int tid = threadIdx.x;
    int w = tid >> 6, lane = tid & 63;
    int base = tid * 8;

    unsigned v[8];
    unsigned s = 0;
    float es = 0.f;
    #pragma unroll
    for (int i = 0; i < 8; ++i) {
        v[i] = counts[base + i];
        s += v[i];
        float e = ema_count[base + i];
        es += e;
        newCount_out[base + i] = 0.99f * e + OMD * (float)v[i];
    }
    float L = lossPart[tid] + lossPart[tid + 1024] + lossPart[tid + 2048] + lossPart[tid + 3072];

    // wave-inclusive scan of s (no barriers; wave64-synchronous)
    unsigned sc = s;
    #pragma unroll
    for (int off = 1; off <= 32; off <<= 1) {
        unsigned t = __shfl_up(sc, off, 64);
        if (lane >= off) sc += t;
    }
    // wave reductions for es, L
    #pragma unroll
    for (int off = 32; off; off >>= 1) {
        es += __shfl_down(es, off, 64);
        L += __shfl_down(L, off, 64);
    }
    if (lane == 63) wsum[w] = sc;
    if (lane == 0) { wes[w] = es; wls[w] = L; }
    __syncthreads();

    if (tid < 16) {
        unsigned t = wsum[tid];
        unsigned tc = t;
        #pragma unroll
        for (int off = 1; off <= 8; off <<= 1) {
            unsigned u = __shfl_up(tc, off, 16);
            if (tid >= off) tc += u;
        }
        wsum[tid] = tc - t;   // exclusive cross-wave offset
        float e2 = wes[tid], l2 = wls[tid];
        #pragma unroll
        for (int off = 8; off; off >>= 1) {
            e2 += __shfl_down(e2, off, 16);
            l2 += __shfl_down(l2, off, 16);
        }
        if (tid == 0) {
            nOut[0] = 0.99f * e2 + OMD * (float)N_ROWS;
            loss_out[0] = 1.25f * l2 / 4194304.0f;
        }
    }
    __syncthreads();

    unsigned run = wsum[w] + (sc - s);   // global exclusive prefix
    #pragma unroll
    for (int i = 0; i < 8; ++i) {
        cursor[base + i] = run;
        run += v[i];
    }
}

// ---------------- scatter rows into code-sorted bucket list ----------------
__global__ __launch_bounds__(256) void scatter_kernel(const unsigned* __restrict__ rowcode,
                                                      unsigned* __restrict__ cursor,
                                                      unsigned* __restrict__ bucketRows,
                                                      unsigned* __restrict__ bucketCodes) {
    int row = blockIdx.x * 256 + threadIdx.x;
    unsigned code = rowcode[row];
    unsigned pos = atomicAdd(cursor + code, 1u);
    bucketRows[pos] = row;
    bucketCodes[pos] = code;
}

// ---------------- bucket_sum: work-balanced segmented reduction over entries ----------------
__global__ __launch_bounds__(256) void bucket_sum_kernel(const float* __restrict__ z,
                                                         const unsigned* __restrict__ bucketRows,
                                                         const unsigned* __restrict__ bucketCodes,
                                                         float* __restrict__ meanAcc) {
    int w = threadIdx.x >> 6, lane = threadIdx.x & 63;
    int base = (blockIdx.x * 4 + w) * 8;

    float4 acc = {0.f, 0.f, 0.f, 0.f};
    unsigned cur = bucketCodes[base];
    #pragma unroll
    for (int e = 0; e < 8; ++e) {
        int p = base + e;
        unsigned code = bucketCodes[p];
        if (code != cur) {
            float* mp = meanAcc + (size_t)cur * DIM + lane * 4;
            atomicAdd(mp + 0, acc.x);
            atomicAdd(mp + 1, acc.y);
            atomicAdd(mp + 2, acc.z);
            atomicAdd(mp + 3, acc.w);
            acc.x = acc.y = acc.z = acc.w = 0.f;
            cur = code;
        }
        unsigned r = bucketRows[p];
        float4 zv = *(const float4*)(z + (size_t)r * DIM + lane * 4);
        acc.x += zv.x; acc.y += zv.y; acc.z += zv.z; acc.w += zv.w;
    }
    float* mp = meanAcc + (size_t)cur * DIM + lane * 4;
    atomicAdd(mp + 0, acc.x);
    atomicAdd(mp + 1, acc.y);
    atomicAdd(mp + 2, acc.z);
    atomicAdd(mp + 3, acc.w);
}

// ---------------- merge: new_mean + new_codebook (streaming) ----------------
__global__ __launch_bounds__(256) void merge_kernel(const float* __restrict__ ema_mean,
                                                    const float* __restrict__ meanAcc,
                                                    const float* __restrict__ newCount,
                                                    const float* __restrict__ nPtr,
                                                    float* __restrict__ newMean_out,
                                                    float* __restrict__ newCb_out) {
    int g = blockIdx.x * 256 + threadIdx.x;
    int k = g >> 6;
    int c4 = (g & 63) * 4;
    float n = nPtr[0];
    float nc = newCount[k];
    float cs = (nc + 1e-5f) / (n + (float)(K_CODES * 1e-5)) * n;
    size_t base = (size_t)k * DIM + c4;
    float4 em = *(const float4*)(ema_mean + base);
    float4 mm = *(const float4*)(meanAcc + base);
    float4 nm;
    nm.x = 0.99f * em.x + 0.01f * mm.x;
    nm.y = 0.99f * em.y + 0.01f * mm.y;
    nm.z = 0.99f * em.z + 0.01f * mm.z;
    nm.w = 0.99f * em.w + 0.01f * mm.w;
    *(float4*)(newMean_out + base) = nm;
    float4 cbv;
    cbv.x = nm.x / cs;
    cbv.y = nm.y / cs;
    cbv.z = nm.z / cs;
    cbv.w = nm.w / cs;
    *(float4*)(newCb_out + base) = cbv;
}

extern "C" void kernel_launch(void* const* d_in, const int* in_sizes, int n_in,
                              void* d_out, int out_size, void* d_ws, size_t ws_size,
                              hipStream_t stream) {
    const float* z         = (const float*)d_in[0];
    const float* cb        = (const float*)d_in[1];
    const float* ema_count = (const float*)d_in[2];
    const float* ema_mean  = (const float*)d_in[3];
    float* out = (float*)d_out;
    char* ws = (char*)d_ws;

    unsigned* counts  = (unsigned*)(ws + WS_CNT);
    unsigned* cn8     = (unsigned*)(ws + WS_CN8);
    float* lossPart   = (float*)(ws + WS_LOSSP);
    float* nPtr       = (float*)(ws + WS_N);
    float* meanAcc    = (float*)(ws + WS_MEAN);
    unsigned* cursor  = (unsigned*)(ws + WS_CUR);
    unsigned* rowcode = (unsigned*)(ws + WS_ROWC);

    signed char* zqp = (signed char*)(out + POFF_ZQP);
    signed char* cqp = (signed char*)(out + POFF_CQP);
    unsigned* cand  = (unsigned*)(out + POFF_CAND);
    unsigned* brows = (unsigned*)(out + POFF_BROWS);   // aliases cand: used post-rescore
    unsigned* bcode = (unsigned*)(out + POFF_BCODE);

    prep_kernel<<<4097, 256, 0, stream>>>(z, cb, zqp, cqp, cn8, meanAcc, counts);
    dist_kernel<<<8192, 256, 0, stream>>>(zqp, cqp, cn8, cand);
    rescore_kernel<<<N_ROWS / 4, 256, 0, stream>>>(z, cb, cand, out + OFF_ZQ, out + OFF_IDX,
                                                   rowcode, counts, lossPart);
    prefix_kernel<<<1, 1024, 0, stream>>>(counts, ema_count, lossPart, cursor,
                                          out + OFF_CNT, nPtr, out + OFF_LOSS);
    scatter_kernel<<<N_ROWS / 256, 256, 0, stream>>>(rowcode, cursor, brows, bcode);
    bucket_sum_kernel<<<512, 256, 0, stream>>>(z, brows, bcode, meanAcc);
    merge_kernel<<<(K_CODES * DIM / 4) / 256, 256, 0, stream>>>(ema_mean, meanAcc,
                                                                out + OFF_CNT, nPtr,
                                                                out + OFF_MEAN, out + OFF_CB);
}